// Round 3
// baseline (589.804 us; speedup 1.0000x reference)
//
#include <hip/hip_runtime.h>
#include <hip/hip_fp16.h>
#include <math.h>

#define EPSf 1e-12f

typedef float v2f __attribute__((ext_vector_type(2)));

__device__ __forceinline__ v2f v2fma(v2f a, v2f b, v2f c) {
  return __builtin_elementwise_fma(a, b, c);
}
__device__ __forceinline__ v2f mkv2(float a, float b) { v2f r; r.x = a; r.y = b; return r; }
__device__ __forceinline__ v2f v2max(v2f a, v2f b) { return __builtin_elementwise_max(a, b); }

// C = X * Y, 4x4 row-major stored as v2f[8] (row i: [2i]=cols01, [2i+1]=cols23)
__device__ __forceinline__ void mm4v(v2f* C, const v2f* X, const v2f* Y) {
#pragma unroll
  for (int i = 0; i < 4; ++i) {
    float x0 = X[2*i].x, x1 = X[2*i].y, x2 = X[2*i+1].x, x3 = X[2*i+1].y;
#pragma unroll
    for (int jp = 0; jp < 2; ++jp) {
      v2f acc = mkv2(x0, x0) * Y[0 + jp];
      acc = v2fma(mkv2(x1, x1), Y[2 + jp], acc);
      acc = v2fma(mkv2(x2, x2), Y[4 + jp], acc);
      acc = v2fma(mkv2(x3, x3), Y[6 + jp], acc);
      C[2*i + jp] = acc;
    }
  }
}
// C += X * Y
__device__ __forceinline__ void mm4v_acc(v2f* C, const v2f* X, const v2f* Y) {
#pragma unroll
  for (int i = 0; i < 4; ++i) {
    float x0 = X[2*i].x, x1 = X[2*i].y, x2 = X[2*i+1].x, x3 = X[2*i+1].y;
#pragma unroll
    for (int jp = 0; jp < 2; ++jp) {
      v2f acc = C[2*i + jp];
      acc = v2fma(mkv2(x0, x0), Y[0 + jp], acc);
      acc = v2fma(mkv2(x1, x1), Y[2 + jp], acc);
      acc = v2fma(mkv2(x2, x2), Y[4 + jp], acc);
      acc = v2fma(mkv2(x3, x3), Y[6 + jp], acc);
      C[2*i + jp] = acc;
    }
  }
}

// expm(Q t) @ f via scaled Taylor-8 (theta=1.5) + repeated squaring.
// y = clip(P,1e-30) @ f ; dy = Q @ y  (= d(P@f)/dt exactly, since dP/dt = Q P)
__device__ __forceinline__ void site_branch(const v2f* Qm, const v2f* Q2, const v2f* Q3,
                                            const v2f* Q4, float L1Q, float t,
                                            const float* f, float* y, float* dy) {
  float r = L1Q * t * 0.66666667f;  // / 1.5
  int m = 0;
  if (r > 1.f) {
    unsigned u = __float_as_uint(r);
    m = (int)(u >> 23) - 127 + (((u & 0x7fffffu) != 0u) ? 1 : 0);
  }
  const float tau = t * __uint_as_float((unsigned)(127 - m) << 23);
  const float t2s = tau * tau, t3s = t2s * tau, t4s = t2s * t2s;
  const float c1 = t2s * 0.5f, c2 = t3s * (1.f/6.f);
  const float d0 = t4s * (1.f/24.f);
  const float d1 = t4s * tau * (1.f/120.f);
  const float d2 = t4s * t2s * (1.f/720.f);
  const float d3 = t4s * t3s * (1.f/5040.f);
  const float d4 = t4s * t4s * (1.f/40320.f);

  // T = I + tau*Q + c1*Q2 + c2*Q3 ;  C1 = d0*I + d1*Q + d2*Q2 + d3*Q3 + d4*Q4
  v2f T[8], C1[8];
#pragma unroll
  for (int ip = 0; ip < 8; ++ip) {
    T[ip]  = v2fma(mkv2(c2,c2), Q3[ip], v2fma(mkv2(c1,c1), Q2[ip], mkv2(tau,tau) * Qm[ip]));
    C1[ip] = v2fma(mkv2(d4,d4), Q4[ip],
             v2fma(mkv2(d3,d3), Q3[ip],
             v2fma(mkv2(d2,d2), Q2[ip], mkv2(d1,d1) * Qm[ip])));
  }
  T[0].x += 1.f;  T[2].y += 1.f;  T[5].x += 1.f;  T[7].y += 1.f;
  C1[0].x += d0;  C1[2].y += d0;  C1[5].x += d0;  C1[7].y += d0;
  mm4v_acc(T, Q4, C1);          // T now = Taylor-8 of expm(Q*tau)

  for (int k = 0; k < m; ++k) {  // divergent trip count: exec-masked, ok
    v2f S[8];
    mm4v(S, T, T);
#pragma unroll
    for (int ip = 0; ip < 8; ++ip) T[ip] = S[ip];
  }

  const v2f f01 = mkv2(f[0], f[1]), f23 = mkv2(f[2], f[3]);
  const v2f lo = mkv2(1e-30f, 1e-30f);
#pragma unroll
  for (int i = 0; i < 4; ++i) {
    v2f a = v2max(T[2*i], lo) * f01;
    a = v2fma(v2max(T[2*i+1], lo), f23, a);
    y[i] = a.x + a.y;
  }
#pragma unroll
  for (int i = 0; i < 4; ++i) {
    v2f a = Qm[2*i] * mkv2(y[0], y[1]);
    a = v2fma(Qm[2*i+1], mkv2(y[2], y[3]), a);
    dy[i] = a.x + a.y;
  }
}

// Prologue: U0h2[s][j-pair] = f16x2 of (b1[j] + sum_k sp[s,k] W1[2+k,j]);
// plus packed 12-column Wq (off-diagonals only; diagonal is discarded by the ref).
__global__ __launch_bounds__(256) void prep_kernel(
    const float* __restrict__ spg, const float* __restrict__ W1g,
    const float* __restrict__ b1g, const float* __restrict__ Wqg,
    const float* __restrict__ bqg,
    __half2* __restrict__ U0h2, float* __restrict__ Wqp, float* __restrict__ bqp)
{
  const int t = blockIdx.x * 256 + threadIdx.x;  // 0..2047
  const int s = t >> 3;                          // site 0..255
  const int jq = t & 7;                          // j-octant
  float spv[16];
#pragma unroll
  for (int k4 = 0; k4 < 4; ++k4) {
    float4 v4 = reinterpret_cast<const float4*>(spg)[s*4 + k4];
    spv[4*k4+0] = v4.x; spv[4*k4+1] = v4.y; spv[4*k4+2] = v4.z; spv[4*k4+3] = v4.w;
  }
#pragma unroll
  for (int jp = 0; jp < 4; ++jp) {
    const int j0 = jq*8 + 2*jp;
    float u0 = b1g[j0], u1 = b1g[j0+1];
#pragma unroll
    for (int k = 0; k < 16; ++k) {
      u0 = fmaf(spv[k], W1g[(2+k)*64 + j0],     u0);
      u1 = fmaf(spv[k], W1g[(2+k)*64 + j0 + 1], u1);
    }
    U0h2[s*32 + jq*4 + jp] = __float22half2_rn(make_float2(u0, u1));
  }
  if (blockIdx.x == 0 && threadIdx.x < 64) {
    const int j = threadIdx.x;
    const int cmap[12] = {1,2,3,4,6,7,8,9,11,12,13,14};
#pragma unroll
    for (int k = 0; k < 12; ++k) Wqp[j*12 + k] = Wqg[j*16 + cmap[k]];
    if (j == 0) {
#pragma unroll
      for (int k = 0; k < 12; ++k) bqp[k] = bqg[cmap[k]];
    }
  }
}

// block = one v (1024 blocks), thread = one site s (256 threads).
__global__ __launch_bounds__(256, 4) void mlme_kernel(
    const float* __restrict__ c1g, const float* __restrict__ c2g,
    const float* __restrict__ lf1g, const float* __restrict__ lf2g,
    const float* __restrict__ W1g,
    const float* __restrict__ Wpg, const float* __restrict__ bpg,
    const __half2* __restrict__ U0h2,
    const float* __restrict__ Wqp, const float* __restrict__ bqp,
    float* __restrict__ outg)
{
  __shared__ float sred[8];
  __shared__ float sAB[2];
  __shared__ float sPQ[8];

  const int v = blockIdx.x;
  const int tid = threadIdx.x;
  const int lane = tid & 63;
  const int wid = tid >> 6;

  if (tid == 0) {
    float c10 = c1g[2*v], c11 = c1g[2*v+1];
    float c20 = c2g[2*v], c21 = c2g[2*v+1];
    float pn = sqrtf(c10*c10 + c11*c11 + EPSf);
    float qn = sqrtf(c20*c20 + c21*c21 + EPSf);
    float p0 = c10, p1 = c11, q0 = c20, q1 = c21;
    if (pn > qn) { float rr = qn/pn; p0 = c10*rr; p1 = c11*rr; }
    if (qn > pn) { float rr = pn/qn; q0 = c20*rr; q1 = c21*rr; }
    sPQ[0]=p0; sPQ[1]=p1; sPQ[2]=q0; sPQ[3]=q1;
    sPQ[4]=c10; sPQ[5]=c11; sPQ[6]=c20; sPQ[7]=c21;
    sAB[0]=0.5f; sAB[1]=0.5f;
  }

  // iteration-invariant per-thread state: u (f16-packed, 32 VGPR) and f=exp(lf)
  __half2 uh[32];
  {
    const __half2* up = U0h2 + tid * 32;
#pragma unroll
    for (int i = 0; i < 32; ++i) uh[i] = up[i];
  }
  float f1[4], f2[4];
  {
    float4 a = reinterpret_cast<const float4*>(lf1g)[v*256 + tid];
    float4 b = reinterpret_cast<const float4*>(lf2g)[v*256 + tid];
    f1[0]=__expf(a.x); f1[1]=__expf(a.y); f1[2]=__expf(a.z); f1[3]=__expf(a.w);
    f2[0]=__expf(b.x); f2[1]=__expf(b.y); f2[2]=__expf(b.z); f2[3]=__expf(b.w);
  }
  __syncthreads();

  const v2f* Wqp2 = reinterpret_cast<const v2f*>(Wqp);   // [j][6]
  const v2f* Wp2  = reinterpret_cast<const v2f*>(Wpg);   // [j][2]
  const v2f* bq2  = reinterpret_cast<const v2f*>(bqp);   // [6]
  const v2f* bp2  = reinterpret_cast<const v2f*>(bpg);   // [2]
  const v2f* W1a2 = reinterpret_cast<const v2f*>(W1g);        // row 0 pairs
  const v2f* W1b2 = reinterpret_cast<const v2f*>(W1g + 64);   // row 1 pairs

#pragma unroll 1
  for (int it = 0; it < 3; ++it) {
    const float alpha = sAB[0], beta = sAB[1];
    const float p0=sPQ[0], p1=sPQ[1], q0=sPQ[2], q1=sPQ[3];
    const float c10=sPQ[4], c11=sPQ[5], c20=sPQ[6], c21=sPQ[7];
    const float mid0 = p0*alpha + q0*(1.f-alpha);
    const float mid1 = p1*alpha + q1*(1.f-alpha);
    const float par0 = mid0*beta, par1 = mid1*beta;
    const float d10 = c10-par0, d11 = c11-par1;
    const float d20 = c20-par0, d21 = c21-par1;
    const float t1 = sqrtf(d10*d10 + d11*d11 + EPSf);
    const float t2 = sqrtf(d20*d20 + d21*d21 + EPSf);

    // ---- MLP: h = relu(u + par.W1[:2]); q/p = h @ [Wqp|Wp] (12+4 cols) ----
    v2f q2[6], p2[2];
#pragma unroll
    for (int k = 0; k < 6; ++k) q2[k] = bq2[k];
    p2[0] = bp2[0]; p2[1] = bp2[1];
    const v2f pz0 = mkv2(par0, par0), pz1 = mkv2(par1, par1);
#pragma unroll
    for (int jp = 0; jp < 32; ++jp) {
      float2 uf = __half22float2(uh[jp]);
      v2f hv = v2fma(pz1, W1b2[jp], v2fma(pz0, W1a2[jp], mkv2(uf.x, uf.y)));
      hv = v2max(hv, mkv2(0.f, 0.f));
      const v2f h0 = mkv2(hv.x, hv.x), h1 = mkv2(hv.y, hv.y);
      const int j0 = 2*jp, j1 = 2*jp + 1;
#pragma unroll
      for (int k = 0; k < 6; ++k) q2[k] = v2fma(h0, Wqp2[j0*6 + k], q2[k]);
      p2[0] = v2fma(h0, Wp2[j0*2 + 0], p2[0]);
      p2[1] = v2fma(h0, Wp2[j0*2 + 1], p2[1]);
#pragma unroll
      for (int k = 0; k < 6; ++k) q2[k] = v2fma(h1, Wqp2[j1*6 + k], q2[k]);
      p2[0] = v2fma(h1, Wp2[j1*2 + 0], p2[0]);
      p2[1] = v2fma(h1, Wp2[j1*2 + 1], p2[1]);
    }

    // ---- softplus on the 12 off-diagonals; build Q and its 1-norm ----
    float o[12];
#pragma unroll
    for (int k = 0; k < 6; ++k) {
      v2f qq = q2[k];
      float x0 = qq.x, x1 = qq.y;
      o[2*k]   = fmaxf(x0, 0.f) + __logf(1.f + __expf(-fabsf(x0)));
      o[2*k+1] = fmaxf(x1, 0.f) + __logf(1.f + __expf(-fabsf(x1)));
    }
    const float rs0 = o[0]+o[1]+o[2],  rs1 = o[3]+o[4]+o[5];
    const float rs2 = o[6]+o[7]+o[8],  rs3 = o[9]+o[10]+o[11];
    v2f Qm[8];
    Qm[0] = mkv2(-rs0, o[0]);  Qm[1] = mkv2(o[1], o[2]);
    Qm[2] = mkv2(o[3], -rs1);  Qm[3] = mkv2(o[4], o[5]);
    Qm[4] = mkv2(o[6], o[7]);  Qm[5] = mkv2(-rs2, o[8]);
    Qm[6] = mkv2(o[9], o[10]); Qm[7] = mkv2(o[11], -rs3);
    const float cs0 = rs0 + o[3] + o[6] + o[9];
    const float cs1 = o[0] + rs1 + o[7] + o[10];
    const float cs2 = o[1] + o[4] + rs2 + o[11];
    const float cs3 = o[2] + o[5] + o[8] + rs3;
    const float L1Q = fmaxf(fmaxf(cs0, cs1), fmaxf(cs2, cs3));

    // unnormalized stationary probs (normalization cancels in gradient ratio)
    float st[4];
    {
      float pr0 = p2[0].x, pr1 = p2[0].y, pr2 = p2[1].x, pr3 = p2[1].y;
      float mx = fmaxf(fmaxf(pr0, pr1), fmaxf(pr2, pr3));
      st[0]=__expf(pr0-mx); st[1]=__expf(pr1-mx); st[2]=__expf(pr2-mx); st[3]=__expf(pr3-mx);
    }

    // shared powers
    v2f Q2m[8], Q3m[8], Q4m[8];
    mm4v(Q2m, Qm, Qm);
    mm4v(Q3m, Q2m, Qm);
    mm4v(Q4m, Q2m, Q2m);

    float y1[4], dy1[4], y2[4], dy2[4];
    site_branch(Qm, Q2m, Q3m, Q4m, L1Q, t1, f1, y1, dy1);
    site_branch(Qm, Q2m, Q3m, Q4m, L1Q, t2, f2, y2, dy2);

    // g_k = sum_a dy_k[a] * (other y)[a] * st[a] / sum_a y1 y2 st
    float den = 0.f, num1 = 0.f, num2 = 0.f;
#pragma unroll
    for (int a = 0; a < 4; ++a) {
      float ys2 = y2[a] * st[a];
      den  = fmaf(y1[a],  ys2, den);
      num1 = fmaf(dy1[a], ys2, num1);
      num2 = fmaf(y1[a] * st[a], dy2[a], num2);
    }
    const float invden = 1.f / den;
    float g1c = num1 * invden;
    float g2c = num2 * invden;

#pragma unroll
    for (int off = 32; off > 0; off >>= 1) {
      g1c += __shfl_xor(g1c, off, 64);
      g2c += __shfl_xor(g2c, off, 64);
    }
    if (lane == 0) { sred[wid*2+0] = g1c; sred[wid*2+1] = g2c; }
    __syncthreads();
    if (tid == 0) {
      float g1 = sred[0]+sred[2]+sred[4]+sred[6];
      float g2 = sred[1]+sred[3]+sred[5]+sred[7];
      float db1da = ((par0-c10)*(p0-q0) + (par1-c11)*(p1-q1)) * beta / t1;
      float db2da = ((par0-c20)*(p0-q0) + (par1-c21)*(p1-q1)) * beta / t2;
      float db1db = ((par0-c10)*mid0 + (par1-c11)*mid1) / t1;
      float db2db = ((par0-c20)*mid0 + (par1-c21)*mid1) / t2;
      float ga = g1*db1da + g2*db2da;
      float gb = g1*db1db + g2*db2db;
      ga = fminf(1.f, fmaxf(-1.f, ga));
      gb = fminf(1.f, fmaxf(-1.f, gb));
      sAB[0] = fminf(1.f, fmaxf(0.f, alpha + 0.1f*ga));
      sAB[1] = fminf(1.f, fmaxf(0.f, beta  + 0.1f*gb));
    }
    __syncthreads();
  }

  if (tid == 0) {
    const float alpha = sAB[0], beta = sAB[1];
    const float p0=sPQ[0], p1=sPQ[1], q0=sPQ[2], q1=sPQ[3];
    float mid0 = p0*alpha + q0*(1.f-alpha);
    float mid1 = p1*alpha + q1*(1.f-alpha);
    outg[2*v]   = mid0*beta;
    outg[2*v+1] = mid1*beta;
  }
}

extern "C" void kernel_launch(void* const* d_in, const int* in_sizes, int n_in,
                              void* d_out, int out_size, void* d_ws, size_t ws_size,
                              hipStream_t stream) {
  (void)in_sizes; (void)n_in; (void)ws_size; (void)out_size;
  const float* c1  = (const float*)d_in[0];
  const float* c2  = (const float*)d_in[1];
  const float* lf1 = (const float*)d_in[2];
  const float* lf2 = (const float*)d_in[3];
  const float* sp  = (const float*)d_in[4];
  const float* W1  = (const float*)d_in[5];
  const float* b1  = (const float*)d_in[6];
  const float* Wq  = (const float*)d_in[7];
  const float* bq  = (const float*)d_in[8];
  const float* Wp  = (const float*)d_in[9];
  const float* bp  = (const float*)d_in[10];
  float* out = (float*)d_out;

  __half2* U0h2 = (__half2*)d_ws;                               // 256*32 = 32 KB
  float*   Wqp  = (float*)((char*)d_ws + 32768);                // 64*12 floats
  float*   bqp  = (float*)((char*)d_ws + 32768 + 64*12*4);      // 12 floats

  prep_kernel<<<dim3(8), dim3(256), 0, stream>>>(sp, W1, b1, Wq, bq, U0h2, Wqp, bqp);
  mlme_kernel<<<dim3(1024), dim3(256), 0, stream>>>(
      c1, c2, lf1, lf2, W1, Wp, bp, U0h2, Wqp, bqp, out);
}

// Round 4
// 222.215 us; speedup vs baseline: 2.6542x; 2.6542x over previous
//
#include <hip/hip_runtime.h>
#include <hip/hip_fp16.h>
#include <math.h>

#define EPSf 1e-12f

typedef float v2f __attribute__((ext_vector_type(2)));

__device__ __forceinline__ v2f v2fma(v2f a, v2f b, v2f c) {
  return __builtin_elementwise_fma(a, b, c);
}
__device__ __forceinline__ v2f mkv2(float a, float b) { v2f r; r.x = a; r.y = b; return r; }
__device__ __forceinline__ v2f v2max(v2f a, v2f b) { return __builtin_elementwise_max(a, b); }

// C = X * Y, 4x4 row-major stored as v2f[8] (row i: [2i]=cols01, [2i+1]=cols23)
__device__ __forceinline__ void mm4v(v2f* C, const v2f* X, const v2f* Y) {
#pragma unroll
  for (int i = 0; i < 4; ++i) {
    float x0 = X[2*i].x, x1 = X[2*i].y, x2 = X[2*i+1].x, x3 = X[2*i+1].y;
#pragma unroll
    for (int jp = 0; jp < 2; ++jp) {
      v2f acc = mkv2(x0, x0) * Y[0 + jp];
      acc = v2fma(mkv2(x1, x1), Y[2 + jp], acc);
      acc = v2fma(mkv2(x2, x2), Y[4 + jp], acc);
      acc = v2fma(mkv2(x3, x3), Y[6 + jp], acc);
      C[2*i + jp] = acc;
    }
  }
}
// C += X * Y
__device__ __forceinline__ void mm4v_acc(v2f* C, const v2f* X, const v2f* Y) {
#pragma unroll
  for (int i = 0; i < 4; ++i) {
    float x0 = X[2*i].x, x1 = X[2*i].y, x2 = X[2*i+1].x, x3 = X[2*i+1].y;
#pragma unroll
    for (int jp = 0; jp < 2; ++jp) {
      v2f acc = C[2*i + jp];
      acc = v2fma(mkv2(x0, x0), Y[0 + jp], acc);
      acc = v2fma(mkv2(x1, x1), Y[2 + jp], acc);
      acc = v2fma(mkv2(x2, x2), Y[4 + jp], acc);
      acc = v2fma(mkv2(x3, x3), Y[6 + jp], acc);
      C[2*i + jp] = acc;
    }
  }
}

// expm(Q t) @ f via scaled Taylor-8 (theta=1.5) + repeated squaring.
// y = clip(P,1e-30) @ f ; dy = Q @ y  (= d(P@f)/dt exactly, since dP/dt = Q P)
__device__ __forceinline__ void site_branch(const v2f* Qm, const v2f* Q2, const v2f* Q3,
                                            const v2f* Q4, float L1Q, float t,
                                            const float* f, float* y, float* dy) {
  float r = L1Q * t * 0.66666667f;  // / 1.5
  int m = 0;
  if (r > 1.f) {
    unsigned u = __float_as_uint(r);
    m = (int)(u >> 23) - 127 + (((u & 0x7fffffu) != 0u) ? 1 : 0);
  }
  const float tau = t * __uint_as_float((unsigned)(127 - m) << 23);
  const float t2s = tau * tau, t3s = t2s * tau, t4s = t2s * t2s;
  const float c1 = t2s * 0.5f, c2 = t3s * (1.f/6.f);
  const float d0 = t4s * (1.f/24.f);
  const float d1 = t4s * tau * (1.f/120.f);
  const float d2 = t4s * t2s * (1.f/720.f);
  const float d3 = t4s * t3s * (1.f/5040.f);
  const float d4 = t4s * t4s * (1.f/40320.f);

  // T = I + tau*Q + c1*Q2 + c2*Q3 ;  C1 = d0*I + d1*Q + d2*Q2 + d3*Q3 + d4*Q4
  v2f T[8], C1[8];
#pragma unroll
  for (int ip = 0; ip < 8; ++ip) {
    T[ip]  = v2fma(mkv2(c2,c2), Q3[ip], v2fma(mkv2(c1,c1), Q2[ip], mkv2(tau,tau) * Qm[ip]));
    C1[ip] = v2fma(mkv2(d4,d4), Q4[ip],
             v2fma(mkv2(d3,d3), Q3[ip],
             v2fma(mkv2(d2,d2), Q2[ip], mkv2(d1,d1) * Qm[ip])));
  }
  T[0].x += 1.f;  T[2].y += 1.f;  T[5].x += 1.f;  T[7].y += 1.f;
  C1[0].x += d0;  C1[2].y += d0;  C1[5].x += d0;  C1[7].y += d0;
  mm4v_acc(T, Q4, C1);          // T now = Taylor-8 of expm(Q*tau)

  for (int k = 0; k < m; ++k) {  // divergent trip count: exec-masked, ok
    v2f S[8];
    mm4v(S, T, T);
#pragma unroll
    for (int ip = 0; ip < 8; ++ip) T[ip] = S[ip];
  }

  const v2f f01 = mkv2(f[0], f[1]), f23 = mkv2(f[2], f[3]);
  const v2f lo = mkv2(1e-30f, 1e-30f);
#pragma unroll
  for (int i = 0; i < 4; ++i) {
    v2f a = v2max(T[2*i], lo) * f01;
    a = v2fma(v2max(T[2*i+1], lo), f23, a);
    y[i] = a.x + a.y;
  }
#pragma unroll
  for (int i = 0; i < 4; ++i) {
    v2f a = Qm[2*i] * mkv2(y[0], y[1]);
    a = v2fma(Qm[2*i+1], mkv2(y[2], y[3]), a);
    dy[i] = a.x + a.y;
  }
}

// Prologue: U0h2[s][j-pair] = f16x2 of (b1[j] + sum_k sp[s,k] W1[2+k,j]);
// plus packed 12-column Wq (off-diagonals only; diagonal is discarded by the ref).
__global__ __launch_bounds__(256) void prep_kernel(
    const float* __restrict__ spg, const float* __restrict__ W1g,
    const float* __restrict__ b1g, const float* __restrict__ Wqg,
    const float* __restrict__ bqg,
    __half2* __restrict__ U0h2, float* __restrict__ Wqp, float* __restrict__ bqp)
{
  const int t = blockIdx.x * 256 + threadIdx.x;  // 0..2047
  const int s = t >> 3;                          // site 0..255
  const int jq = t & 7;                          // j-octant
  float spv[16];
#pragma unroll
  for (int k4 = 0; k4 < 4; ++k4) {
    float4 v4 = reinterpret_cast<const float4*>(spg)[s*4 + k4];
    spv[4*k4+0] = v4.x; spv[4*k4+1] = v4.y; spv[4*k4+2] = v4.z; spv[4*k4+3] = v4.w;
  }
#pragma unroll
  for (int jp = 0; jp < 4; ++jp) {
    const int j0 = jq*8 + 2*jp;
    float u0 = b1g[j0], u1 = b1g[j0+1];
#pragma unroll
    for (int k = 0; k < 16; ++k) {
      u0 = fmaf(spv[k], W1g[(2+k)*64 + j0],     u0);
      u1 = fmaf(spv[k], W1g[(2+k)*64 + j0 + 1], u1);
    }
    U0h2[s*32 + jq*4 + jp] = __float22half2_rn(make_float2(u0, u1));
  }
  if (blockIdx.x == 0 && threadIdx.x < 64) {
    const int j = threadIdx.x;
    const int cmap[12] = {1,2,3,4,6,7,8,9,11,12,13,14};
#pragma unroll
    for (int k = 0; k < 12; ++k) Wqp[j*12 + k] = Wqg[j*16 + cmap[k]];
    if (j == 0) {
#pragma unroll
      for (int k = 0; k < 12; ++k) bqp[k] = bqg[cmap[k]];
    }
  }
}

// block = one v (1024 blocks), thread = one site s (256 threads).
// NOTE: plain __launch_bounds__(256) — R3's (256,4) min-occupancy arg made the
// allocator clamp to 64 VGPR and spill ~1.9 GB to scratch (590 us). R2's plain
// bound allocated 84 VGPR spill-free for heavier state.
__global__ __launch_bounds__(256) void mlme_kernel(
    const float* __restrict__ c1g, const float* __restrict__ c2g,
    const float* __restrict__ lf1g, const float* __restrict__ lf2g,
    const float* __restrict__ W1g,
    const float* __restrict__ Wpg, const float* __restrict__ bpg,
    const __half2* __restrict__ U0h2,
    const float* __restrict__ Wqp, const float* __restrict__ bqp,
    float* __restrict__ outg)
{
  __shared__ float sred[8];
  __shared__ float sAB[2];
  __shared__ float sPQ[8];

  const int v = blockIdx.x;
  const int tid = threadIdx.x;
  const int lane = tid & 63;
  const int wid = tid >> 6;

  if (tid == 0) {
    float c10 = c1g[2*v], c11 = c1g[2*v+1];
    float c20 = c2g[2*v], c21 = c2g[2*v+1];
    float pn = sqrtf(c10*c10 + c11*c11 + EPSf);
    float qn = sqrtf(c20*c20 + c21*c21 + EPSf);
    float p0 = c10, p1 = c11, q0 = c20, q1 = c21;
    if (pn > qn) { float rr = qn/pn; p0 = c10*rr; p1 = c11*rr; }
    if (qn > pn) { float rr = pn/qn; q0 = c20*rr; q1 = c21*rr; }
    sPQ[0]=p0; sPQ[1]=p1; sPQ[2]=q0; sPQ[3]=q1;
    sPQ[4]=c10; sPQ[5]=c11; sPQ[6]=c20; sPQ[7]=c21;
    sAB[0]=0.5f; sAB[1]=0.5f;
  }

  // iteration-invariant per-thread state: u (f16-packed, 32 VGPR) and f=exp(lf)
  __half2 uh[32];
  {
    const __half2* up = U0h2 + tid * 32;
#pragma unroll
    for (int i = 0; i < 32; ++i) uh[i] = up[i];
  }
  float f1[4], f2[4];
  {
    float4 a = reinterpret_cast<const float4*>(lf1g)[v*256 + tid];
    float4 b = reinterpret_cast<const float4*>(lf2g)[v*256 + tid];
    f1[0]=__expf(a.x); f1[1]=__expf(a.y); f1[2]=__expf(a.z); f1[3]=__expf(a.w);
    f2[0]=__expf(b.x); f2[1]=__expf(b.y); f2[2]=__expf(b.z); f2[3]=__expf(b.w);
  }
  __syncthreads();

  const v2f* Wqp2 = reinterpret_cast<const v2f*>(Wqp);   // [j][6]
  const v2f* Wp2  = reinterpret_cast<const v2f*>(Wpg);   // [j][2]
  const v2f* bq2  = reinterpret_cast<const v2f*>(bqp);   // [6]
  const v2f* bp2  = reinterpret_cast<const v2f*>(bpg);   // [2]
  const v2f* W1a2 = reinterpret_cast<const v2f*>(W1g);        // row 0 pairs
  const v2f* W1b2 = reinterpret_cast<const v2f*>(W1g + 64);   // row 1 pairs

#pragma unroll 1
  for (int it = 0; it < 3; ++it) {
    const float alpha = sAB[0], beta = sAB[1];
    const float p0=sPQ[0], p1=sPQ[1], q0=sPQ[2], q1=sPQ[3];
    const float c10=sPQ[4], c11=sPQ[5], c20=sPQ[6], c21=sPQ[7];
    const float mid0 = p0*alpha + q0*(1.f-alpha);
    const float mid1 = p1*alpha + q1*(1.f-alpha);
    const float par0 = mid0*beta, par1 = mid1*beta;
    const float d10 = c10-par0, d11 = c11-par1;
    const float d20 = c20-par0, d21 = c21-par1;
    const float t1 = sqrtf(d10*d10 + d11*d11 + EPSf);
    const float t2 = sqrtf(d20*d20 + d21*d21 + EPSf);

    // ---- MLP: h = relu(u + par.W1[:2]); q/p = h @ [Wqp|Wp] (12+4 cols) ----
    v2f q2[6], p2[2];
#pragma unroll
    for (int k = 0; k < 6; ++k) q2[k] = bq2[k];
    p2[0] = bp2[0]; p2[1] = bp2[1];
    const v2f pz0 = mkv2(par0, par0), pz1 = mkv2(par1, par1);
#pragma unroll
    for (int jp = 0; jp < 32; ++jp) {
      float2 uf = __half22float2(uh[jp]);
      v2f hv = v2fma(pz1, W1b2[jp], v2fma(pz0, W1a2[jp], mkv2(uf.x, uf.y)));
      hv = v2max(hv, mkv2(0.f, 0.f));
      const v2f h0 = mkv2(hv.x, hv.x), h1 = mkv2(hv.y, hv.y);
      const int j0 = 2*jp, j1 = 2*jp + 1;
#pragma unroll
      for (int k = 0; k < 6; ++k) q2[k] = v2fma(h0, Wqp2[j0*6 + k], q2[k]);
      p2[0] = v2fma(h0, Wp2[j0*2 + 0], p2[0]);
      p2[1] = v2fma(h0, Wp2[j0*2 + 1], p2[1]);
#pragma unroll
      for (int k = 0; k < 6; ++k) q2[k] = v2fma(h1, Wqp2[j1*6 + k], q2[k]);
      p2[0] = v2fma(h1, Wp2[j1*2 + 0], p2[0]);
      p2[1] = v2fma(h1, Wp2[j1*2 + 1], p2[1]);
    }

    // ---- softplus on the 12 off-diagonals; build Q and its 1-norm ----
    float o[12];
#pragma unroll
    for (int k = 0; k < 6; ++k) {
      v2f qq = q2[k];
      float x0 = qq.x, x1 = qq.y;
      o[2*k]   = fmaxf(x0, 0.f) + __logf(1.f + __expf(-fabsf(x0)));
      o[2*k+1] = fmaxf(x1, 0.f) + __logf(1.f + __expf(-fabsf(x1)));
    }
    const float rs0 = o[0]+o[1]+o[2],  rs1 = o[3]+o[4]+o[5];
    const float rs2 = o[6]+o[7]+o[8],  rs3 = o[9]+o[10]+o[11];
    v2f Qm[8];
    Qm[0] = mkv2(-rs0, o[0]);  Qm[1] = mkv2(o[1], o[2]);
    Qm[2] = mkv2(o[3], -rs1);  Qm[3] = mkv2(o[4], o[5]);
    Qm[4] = mkv2(o[6], o[7]);  Qm[5] = mkv2(-rs2, o[8]);
    Qm[6] = mkv2(o[9], o[10]); Qm[7] = mkv2(o[11], -rs3);
    const float cs0 = rs0 + o[3] + o[6] + o[9];
    const float cs1 = o[0] + rs1 + o[7] + o[10];
    const float cs2 = o[1] + o[4] + rs2 + o[11];
    const float cs3 = o[2] + o[5] + o[8] + rs3;
    const float L1Q = fmaxf(fmaxf(cs0, cs1), fmaxf(cs2, cs3));

    // unnormalized stationary probs (normalization cancels in gradient ratio)
    float st[4];
    {
      float pr0 = p2[0].x, pr1 = p2[0].y, pr2 = p2[1].x, pr3 = p2[1].y;
      float mx = fmaxf(fmaxf(pr0, pr1), fmaxf(pr2, pr3));
      st[0]=__expf(pr0-mx); st[1]=__expf(pr1-mx); st[2]=__expf(pr2-mx); st[3]=__expf(pr3-mx);
    }

    // shared powers
    v2f Q2m[8], Q3m[8], Q4m[8];
    mm4v(Q2m, Qm, Qm);
    mm4v(Q3m, Q2m, Qm);
    mm4v(Q4m, Q2m, Q2m);

    float y1[4], dy1[4], y2[4], dy2[4];
    site_branch(Qm, Q2m, Q3m, Q4m, L1Q, t1, f1, y1, dy1);
    site_branch(Qm, Q2m, Q3m, Q4m, L1Q, t2, f2, y2, dy2);

    // g_k = sum_a dy_k[a] * (other y)[a] * st[a] / sum_a y1 y2 st
    float den = 0.f, num1 = 0.f, num2 = 0.f;
#pragma unroll
    for (int a = 0; a < 4; ++a) {
      float ys2 = y2[a] * st[a];
      den  = fmaf(y1[a],  ys2, den);
      num1 = fmaf(dy1[a], ys2, num1);
      num2 = fmaf(y1[a] * st[a], dy2[a], num2);
    }
    const float invden = 1.f / den;
    float g1c = num1 * invden;
    float g2c = num2 * invden;

#pragma unroll
    for (int off = 32; off > 0; off >>= 1) {
      g1c += __shfl_xor(g1c, off, 64);
      g2c += __shfl_xor(g2c, off, 64);
    }
    if (lane == 0) { sred[wid*2+0] = g1c; sred[wid*2+1] = g2c; }
    __syncthreads();
    if (tid == 0) {
      float g1 = sred[0]+sred[2]+sred[4]+sred[6];
      float g2 = sred[1]+sred[3]+sred[5]+sred[7];
      float db1da = ((par0-c10)*(p0-q0) + (par1-c11)*(p1-q1)) * beta / t1;
      float db2da = ((par0-c20)*(p0-q0) + (par1-c21)*(p1-q1)) * beta / t2;
      float db1db = ((par0-c10)*mid0 + (par1-c11)*mid1) / t1;
      float db2db = ((par0-c20)*mid0 + (par1-c21)*mid1) / t2;
      float ga = g1*db1da + g2*db2da;
      float gb = g1*db1db + g2*db2db;
      ga = fminf(1.f, fmaxf(-1.f, ga));
      gb = fminf(1.f, fmaxf(-1.f, gb));
      sAB[0] = fminf(1.f, fmaxf(0.f, alpha + 0.1f*ga));
      sAB[1] = fminf(1.f, fmaxf(0.f, beta  + 0.1f*gb));
    }
    __syncthreads();
  }

  if (tid == 0) {
    const float alpha = sAB[0], beta = sAB[1];
    const float p0=sPQ[0], p1=sPQ[1], q0=sPQ[2], q1=sPQ[3];
    float mid0 = p0*alpha + q0*(1.f-alpha);
    float mid1 = p1*alpha + q1*(1.f-alpha);
    outg[2*v]   = mid0*beta;
    outg[2*v+1] = mid1*beta;
  }
}

extern "C" void kernel_launch(void* const* d_in, const int* in_sizes, int n_in,
                              void* d_out, int out_size, void* d_ws, size_t ws_size,
                              hipStream_t stream) {
  (void)in_sizes; (void)n_in; (void)ws_size; (void)out_size;
  const float* c1  = (const float*)d_in[0];
  const float* c2  = (const float*)d_in[1];
  const float* lf1 = (const float*)d_in[2];
  const float* lf2 = (const float*)d_in[3];
  const float* sp  = (const float*)d_in[4];
  const float* W1  = (const float*)d_in[5];
  const float* b1  = (const float*)d_in[6];
  const float* Wq  = (const float*)d_in[7];
  const float* bq  = (const float*)d_in[8];
  const float* Wp  = (const float*)d_in[9];
  const float* bp  = (const float*)d_in[10];
  float* out = (float*)d_out;

  __half2* U0h2 = (__half2*)d_ws;                               // 256*32 = 32 KB
  float*   Wqp  = (float*)((char*)d_ws + 32768);                // 64*12 floats
  float*   bqp  = (float*)((char*)d_ws + 32768 + 64*12*4);      // 12 floats

  prep_kernel<<<dim3(8), dim3(256), 0, stream>>>(sp, W1, b1, Wq, bq, U0h2, Wqp, bqp);
  mlme_kernel<<<dim3(1024), dim3(256), 0, stream>>>(
      c1, c2, lf1, lf2, W1, Wp, bp, U0h2, Wqp, bqp, out);
}

// Round 5
// 66.011 us; speedup vs baseline: 8.9349x; 3.3663x over previous
//
#include <hip/hip_runtime.h>
#include <math.h>

#define EPSf 1e-12f

typedef float v2f __attribute__((ext_vector_type(2)));

__device__ __forceinline__ v2f v2fma(v2f a, v2f b, v2f c) {
  return __builtin_elementwise_fma(a, b, c);
}
__device__ __forceinline__ v2f mkv2(float a, float b) { v2f r; r.x = a; r.y = b; return r; }
__device__ __forceinline__ v2f v2max(v2f a, v2f b) { return __builtin_elementwise_max(a, b); }

// C = X * Y, 4x4 row-major stored as v2f[8] (row i: [2i]=cols01, [2i+1]=cols23)
__device__ __forceinline__ void mm4v(v2f* C, const v2f* X, const v2f* Y) {
#pragma unroll
  for (int i = 0; i < 4; ++i) {
    float x0 = X[2*i].x, x1 = X[2*i].y, x2 = X[2*i+1].x, x3 = X[2*i+1].y;
#pragma unroll
    for (int jp = 0; jp < 2; ++jp) {
      v2f acc = mkv2(x0, x0) * Y[0 + jp];
      acc = v2fma(mkv2(x1, x1), Y[2 + jp], acc);
      acc = v2fma(mkv2(x2, x2), Y[4 + jp], acc);
      acc = v2fma(mkv2(x3, x3), Y[6 + jp], acc);
      C[2*i + jp] = acc;
    }
  }
}
// C += X * Y
__device__ __forceinline__ void mm4v_acc(v2f* C, const v2f* X, const v2f* Y) {
#pragma unroll
  for (int i = 0; i < 4; ++i) {
    float x0 = X[2*i].x, x1 = X[2*i].y, x2 = X[2*i+1].x, x3 = X[2*i+1].y;
#pragma unroll
    for (int jp = 0; jp < 2; ++jp) {
      v2f acc = C[2*i + jp];
      acc = v2fma(mkv2(x0, x0), Y[0 + jp], acc);
      acc = v2fma(mkv2(x1, x1), Y[2 + jp], acc);
      acc = v2fma(mkv2(x2, x2), Y[4 + jp], acc);
      acc = v2fma(mkv2(x3, x3), Y[6 + jp], acc);
      C[2*i + jp] = acc;
    }
  }
}

// expm(Q t) @ f via scaled Taylor-8 (theta=1.5) + repeated squaring.
// y = clip(P,1e-30) @ f ; dy = Q @ y  (exact: dP/dt = Q P)
__device__ __forceinline__ void site_branch(const v2f* Qm, const v2f* Q2, const v2f* Q3,
                                            const v2f* Q4, float L1Q, float t,
                                            const float* f, float* y, float* dy) {
  float r = L1Q * t * 0.66666667f;  // / 1.5
  int m = 0;
  if (r > 1.f) {
    unsigned u = __float_as_uint(r);
    m = (int)(u >> 23) - 127 + (((u & 0x7fffffu) != 0u) ? 1 : 0);
  }
  const float tau = t * __uint_as_float((unsigned)(127 - m) << 23);
  const float t2s = tau * tau, t3s = t2s * tau, t4s = t2s * t2s;
  const float c1 = t2s * 0.5f, c2 = t3s * (1.f/6.f);
  const float d0 = t4s * (1.f/24.f);
  const float d1 = t4s * tau * (1.f/120.f);
  const float d2 = t4s * t2s * (1.f/720.f);
  const float d3 = t4s * t3s * (1.f/5040.f);
  const float d4 = t4s * t4s * (1.f/40320.f);

  // T = I + tau*Q + c1*Q2 + c2*Q3 ; C1 = d0*I + d1*Q + d2*Q2 + d3*Q3 + d4*Q4
  v2f T[8], C1[8];
#pragma unroll
  for (int ip = 0; ip < 8; ++ip) {
    T[ip]  = v2fma(mkv2(c2,c2), Q3[ip], v2fma(mkv2(c1,c1), Q2[ip], mkv2(tau,tau) * Qm[ip]));
    C1[ip] = v2fma(mkv2(d4,d4), Q4[ip],
             v2fma(mkv2(d3,d3), Q3[ip],
             v2fma(mkv2(d2,d2), Q2[ip], mkv2(d1,d1) * Qm[ip])));
  }
  T[0].x += 1.f;  T[2].y += 1.f;  T[5].x += 1.f;  T[7].y += 1.f;
  C1[0].x += d0;  C1[2].y += d0;  C1[5].x += d0;  C1[7].y += d0;
  mm4v_acc(T, Q4, C1);           // T = Taylor-8 of expm(Q*tau)

  for (int k = 0; k < m; ++k) {  // divergent trip count: exec-masked, ok
    v2f S[8];
    mm4v(S, T, T);
#pragma unroll
    for (int ip = 0; ip < 8; ++ip) T[ip] = S[ip];
  }

  const v2f f01 = mkv2(f[0], f[1]), f23 = mkv2(f[2], f[3]);
  const v2f lo = mkv2(1e-30f, 1e-30f);
#pragma unroll
  for (int i = 0; i < 4; ++i) {
    v2f a = v2max(T[2*i], lo) * f01;
    a = v2fma(v2max(T[2*i+1], lo), f23, a);
    y[i] = a.x + a.y;
  }
#pragma unroll
  for (int i = 0; i < 4; ++i) {
    v2f a = Qm[2*i] * mkv2(y[0], y[1]);
    a = v2fma(Qm[2*i+1], mkv2(y[2], y[3]), a);
    dy[i] = a.x + a.y;
  }
}

// Prologue A: U0T[j][s] = b1[j] + sum_k sp[s,k]*W1[2+k,j]  (f32, like R2)
__global__ __launch_bounds__(256) void u0_kernel(const float* __restrict__ spg,
                                                 const float* __restrict__ W1g,
                                                 const float* __restrict__ b1g,
                                                 float* __restrict__ U0T,
                                                 float* __restrict__ Wqp,
                                                 float* __restrict__ bqp) {
  const int j = blockIdx.x;     // 0..63 (wave-uniform -> W1 via s_load)
  const int s = threadIdx.x;    // 0..255
  float acc = b1g[j];
#pragma unroll
  for (int k = 0; k < 16; ++k) acc = fmaf(spg[s*16 + k], W1g[(2 + k)*64 + j], acc);
  U0T[j*256 + s] = acc;
  // pack the 12 off-diagonal Wq columns (diagonal is discarded by (1-eye))
  if (blockIdx.x == 0 && threadIdx.x < 64) {
    // note: reuse of Wqg would need it as an arg; done in a second tiny kernel below
  }
}

__global__ __launch_bounds__(64) void wq_pack_kernel(const float* __restrict__ Wqg,
                                                     const float* __restrict__ bqg,
                                                     float* __restrict__ Wqp,
                                                     float* __restrict__ bqp) {
  const int j = threadIdx.x;  // 0..63
  const int cmap[12] = {1,2,3,4,6,7,8,9,11,12,13,14};
#pragma unroll
  for (int k = 0; k < 12; ++k) Wqp[j*12 + k] = Wqg[j*16 + cmap[k]];
  if (j == 0) {
#pragma unroll
    for (int k = 0; k < 12; ++k) bqp[k] = bqg[cmap[k]];
  }
}

// block = one v (1024 blocks), thread = one site s (256 threads).
// Plain __launch_bounds__(256): R3's (256,4) caused 64-VGPR clamp + 1.9 GB spill;
// R4's register hoists caused 196 VGPR + occupancy collapse. R2-style structure
// (u reloaded from global each iteration) keeps VGPR in the good tier.
__global__ __launch_bounds__(256) void mlme_kernel(
    const float* __restrict__ c1g, const float* __restrict__ c2g,
    const float* __restrict__ lf1g, const float* __restrict__ lf2g,
    const float* __restrict__ W1g,
    const float* __restrict__ Wpg, const float* __restrict__ bpg,
    const float* __restrict__ U0T,
    const float* __restrict__ Wqp, const float* __restrict__ bqp,
    float* __restrict__ outg)
{
  __shared__ float sred[8];
  __shared__ float sAB[2];
  __shared__ float sPQ[8];

  const int v = blockIdx.x;
  const int tid = threadIdx.x;
  const int lane = tid & 63;
  const int wid = tid >> 6;

  if (tid == 0) {
    float c10 = c1g[2*v], c11 = c1g[2*v+1];
    float c20 = c2g[2*v], c21 = c2g[2*v+1];
    float pn = sqrtf(c10*c10 + c11*c11 + EPSf);
    float qn = sqrtf(c20*c20 + c21*c21 + EPSf);
    float p0 = c10, p1 = c11, q0 = c20, q1 = c21;
    if (pn > qn) { float rr = qn/pn; p0 = c10*rr; p1 = c11*rr; }
    if (qn > pn) { float rr = pn/qn; q0 = c20*rr; q1 = c21*rr; }
    sPQ[0]=p0; sPQ[1]=p1; sPQ[2]=q0; sPQ[3]=q1;
    sPQ[4]=c10; sPQ[5]=c11; sPQ[6]=c20; sPQ[7]=c21;
    sAB[0]=0.5f; sAB[1]=0.5f;
  }

  // f = exp(log_felsenstein) per thread, once
  float f1[4], f2[4];
  {
    float4 a = reinterpret_cast<const float4*>(lf1g)[v*256 + tid];
    float4 b = reinterpret_cast<const float4*>(lf2g)[v*256 + tid];
    f1[0]=__expf(a.x); f1[1]=__expf(a.y); f1[2]=__expf(a.z); f1[3]=__expf(a.w);
    f2[0]=__expf(b.x); f2[1]=__expf(b.y); f2[2]=__expf(b.z); f2[3]=__expf(b.w);
  }
  __syncthreads();

  const v2f* Wqp2 = reinterpret_cast<const v2f*>(Wqp);   // [j][6]
  const v2f* Wp2  = reinterpret_cast<const v2f*>(Wpg);   // [j][2]
  const v2f* bq2  = reinterpret_cast<const v2f*>(bqp);   // [6]
  const v2f* bp2  = reinterpret_cast<const v2f*>(bpg);   // [2]

  for (int it = 0; it < 3; ++it) {
    const float alpha = sAB[0], beta = sAB[1];
    const float p0=sPQ[0], p1=sPQ[1], q0=sPQ[2], q1=sPQ[3];
    const float c10=sPQ[4], c11=sPQ[5], c20=sPQ[6], c21=sPQ[7];
    const float mid0 = p0*alpha + q0*(1.f-alpha);
    const float mid1 = p1*alpha + q1*(1.f-alpha);
    const float par0 = mid0*beta, par1 = mid1*beta;
    const float d10 = c10-par0, d11 = c11-par1;
    const float d20 = c20-par0, d21 = c21-par1;
    const float t1 = sqrtf(d10*d10 + d11*d11 + EPSf);
    const float t2 = sqrtf(d20*d20 + d21*d21 + EPSf);

    // ---- MLP: h = relu(u + par.W1[:2]); 12 q-cols + 4 p-cols ----
    v2f q2[6], p2[2];
#pragma unroll
    for (int k = 0; k < 6; ++k) q2[k] = bq2[k];
    p2[0] = bp2[0]; p2[1] = bp2[1];
#pragma unroll 4
    for (int j = 0; j < 64; ++j) {
      float u = U0T[j*256 + tid];
      float h = fmaxf(fmaf(par1, W1g[64 + j], fmaf(par0, W1g[j], u)), 0.f);
      v2f hh = mkv2(h, h);
#pragma unroll
      for (int k = 0; k < 6; ++k) q2[k] = v2fma(hh, Wqp2[j*6 + k], q2[k]);
      p2[0] = v2fma(hh, Wp2[j*2 + 0], p2[0]);
      p2[1] = v2fma(hh, Wp2[j*2 + 1], p2[1]);
    }

    // ---- softplus on the 12 off-diagonals; build Q and its 1-norm ----
    float o[12];
#pragma unroll
    for (int k = 0; k < 6; ++k) {
      v2f qq = q2[k];
      float x0 = qq.x, x1 = qq.y;
      o[2*k]   = fmaxf(x0, 0.f) + __logf(1.f + __expf(-fabsf(x0)));
      o[2*k+1] = fmaxf(x1, 0.f) + __logf(1.f + __expf(-fabsf(x1)));
    }
    const float rs0 = o[0]+o[1]+o[2],  rs1 = o[3]+o[4]+o[5];
    const float rs2 = o[6]+o[7]+o[8],  rs3 = o[9]+o[10]+o[11];
    v2f Qm[8];
    Qm[0] = mkv2(-rs0, o[0]);  Qm[1] = mkv2(o[1], o[2]);
    Qm[2] = mkv2(o[3], -rs1);  Qm[3] = mkv2(o[4], o[5]);
    Qm[4] = mkv2(o[6], o[7]);  Qm[5] = mkv2(-rs2, o[8]);
    Qm[6] = mkv2(o[9], o[10]); Qm[7] = mkv2(o[11], -rs3);
    const float cs0 = rs0 + o[3] + o[6] + o[9];
    const float cs1 = o[0] + rs1 + o[7] + o[10];
    const float cs2 = o[1] + o[4] + rs2 + o[11];
    const float cs3 = o[2] + o[5] + o[8] + rs3;
    const float L1Q = fmaxf(fmaxf(cs0, cs1), fmaxf(cs2, cs3));

    // unnormalized stationary probs (normalization cancels in gradient ratio)
    float st[4];
    {
      float pr0 = p2[0].x, pr1 = p2[0].y, pr2 = p2[1].x, pr3 = p2[1].y;
      float mx = fmaxf(fmaxf(pr0, pr1), fmaxf(pr2, pr3));
      st[0]=__expf(pr0-mx); st[1]=__expf(pr1-mx); st[2]=__expf(pr2-mx); st[3]=__expf(pr3-mx);
    }

    // shared powers
    v2f Q2m[8], Q3m[8], Q4m[8];
    mm4v(Q2m, Qm, Qm);
    mm4v(Q3m, Q2m, Qm);
    mm4v(Q4m, Q2m, Q2m);

    float y1[4], dy1[4], y2[4], dy2[4];
    site_branch(Qm, Q2m, Q3m, Q4m, L1Q, t1, f1, y1, dy1);
    site_branch(Qm, Q2m, Q3m, Q4m, L1Q, t2, f2, y2, dy2);

    // g_k = sum_a dy_k[a] * (other y)[a] * st[a] / sum_a y1 y2 st
    float den = 0.f, num1 = 0.f, num2 = 0.f;
#pragma unroll
    for (int a = 0; a < 4; ++a) {
      float ys2 = y2[a] * st[a];
      den  = fmaf(y1[a],  ys2, den);
      num1 = fmaf(dy1[a], ys2, num1);
      num2 = fmaf(y1[a] * st[a], dy2[a], num2);
    }
    const float invden = 1.f / den;
    float g1c = num1 * invden;
    float g2c = num2 * invden;

#pragma unroll
    for (int off = 32; off > 0; off >>= 1) {
      g1c += __shfl_xor(g1c, off, 64);
      g2c += __shfl_xor(g2c, off, 64);
    }
    if (lane == 0) { sred[wid*2+0] = g1c; sred[wid*2+1] = g2c; }
    __syncthreads();
    if (tid == 0) {
      float g1 = sred[0]+sred[2]+sred[4]+sred[6];
      float g2 = sred[1]+sred[3]+sred[5]+sred[7];
      float db1da = ((par0-c10)*(p0-q0) + (par1-c11)*(p1-q1)) * beta / t1;
      float db2da = ((par0-c20)*(p0-q0) + (par1-c21)*(p1-q1)) * beta / t2;
      float db1db = ((par0-c10)*mid0 + (par1-c11)*mid1) / t1;
      float db2db = ((par0-c20)*mid0 + (par1-c21)*mid1) / t2;
      float ga = g1*db1da + g2*db2da;
      float gb = g1*db1db + g2*db2db;
      ga = fminf(1.f, fmaxf(-1.f, ga));
      gb = fminf(1.f, fmaxf(-1.f, gb));
      sAB[0] = fminf(1.f, fmaxf(0.f, alpha + 0.1f*ga));
      sAB[1] = fminf(1.f, fmaxf(0.f, beta  + 0.1f*gb));
    }
    __syncthreads();
  }

  if (tid == 0) {
    const float alpha = sAB[0], beta = sAB[1];
    const float p0=sPQ[0], p1=sPQ[1], q0=sPQ[2], q1=sPQ[3];
    float mid0 = p0*alpha + q0*(1.f-alpha);
    float mid1 = p1*alpha + q1*(1.f-alpha);
    outg[2*v]   = mid0*beta;
    outg[2*v+1] = mid1*beta;
  }
}

extern "C" void kernel_launch(void* const* d_in, const int* in_sizes, int n_in,
                              void* d_out, int out_size, void* d_ws, size_t ws_size,
                              hipStream_t stream) {
  (void)in_sizes; (void)n_in; (void)ws_size; (void)out_size;
  const float* c1  = (const float*)d_in[0];
  const float* c2  = (const float*)d_in[1];
  const float* lf1 = (const float*)d_in[2];
  const float* lf2 = (const float*)d_in[3];
  const float* sp  = (const float*)d_in[4];
  const float* W1  = (const float*)d_in[5];
  const float* b1  = (const float*)d_in[6];
  const float* Wq  = (const float*)d_in[7];
  const float* bq  = (const float*)d_in[8];
  const float* Wp  = (const float*)d_in[9];
  const float* bp  = (const float*)d_in[10];
  float* out = (float*)d_out;

  float* U0T = (float*)d_ws;                              // 64*256 f32 = 64 KB
  float* Wqp = (float*)((char*)d_ws + 65536);             // 64*12 floats
  float* bqp = (float*)((char*)d_ws + 65536 + 64*12*4);   // 12 floats

  u0_kernel<<<dim3(64), dim3(256), 0, stream>>>(sp, W1, b1, U0T, Wqp, bqp);
  wq_pack_kernel<<<dim3(1), dim3(64), 0, stream>>>(Wq, bq, Wqp, bqp);
  mlme_kernel<<<dim3(1024), dim3(256), 0, stream>>>(
      c1, c2, lf1, lf2, W1, Wp, bp, U0T, Wqp, bqp, out);
}

// Round 6
// 64.500 us; speedup vs baseline: 9.1442x; 1.0234x over previous
//
#include <hip/hip_runtime.h>
#include <hip/hip_fp16.h>
#include <math.h>

#define EPSf 1e-12f

typedef float v2f __attribute__((ext_vector_type(2)));

__device__ __forceinline__ v2f v2fma(v2f a, v2f b, v2f c) {
  return __builtin_elementwise_fma(a, b, c);
}
__device__ __forceinline__ v2f mkv2(float a, float b) { v2f r; r.x = a; r.y = b; return r; }
__device__ __forceinline__ v2f v2max(v2f a, v2f b) { return __builtin_elementwise_max(a, b); }

// C = X * Y, 4x4 row-major stored as v2f[8] (row i: [2i]=cols01, [2i+1]=cols23)
__device__ __forceinline__ void mm4v(v2f* C, const v2f* X, const v2f* Y) {
#pragma unroll
  for (int i = 0; i < 4; ++i) {
    float x0 = X[2*i].x, x1 = X[2*i].y, x2 = X[2*i+1].x, x3 = X[2*i+1].y;
#pragma unroll
    for (int jp = 0; jp < 2; ++jp) {
      v2f acc = mkv2(x0, x0) * Y[0 + jp];
      acc = v2fma(mkv2(x1, x1), Y[2 + jp], acc);
      acc = v2fma(mkv2(x2, x2), Y[4 + jp], acc);
      acc = v2fma(mkv2(x3, x3), Y[6 + jp], acc);
      C[2*i + jp] = acc;
    }
  }
}
// C += X * Y
__device__ __forceinline__ void mm4v_acc(v2f* C, const v2f* X, const v2f* Y) {
#pragma unroll
  for (int i = 0; i < 4; ++i) {
    float x0 = X[2*i].x, x1 = X[2*i].y, x2 = X[2*i+1].x, x3 = X[2*i+1].y;
#pragma unroll
    for (int jp = 0; jp < 2; ++jp) {
      v2f acc = C[2*i + jp];
      acc = v2fma(mkv2(x0, x0), Y[0 + jp], acc);
      acc = v2fma(mkv2(x1, x1), Y[2 + jp], acc);
      acc = v2fma(mkv2(x2, x2), Y[4 + jp], acc);
      acc = v2fma(mkv2(x3, x3), Y[6 + jp], acc);
      C[2*i + jp] = acc;
    }
  }
}

// expm(Q t) @ f via scaled Taylor-8 (theta=1.5) + repeated squaring.
// y = clip(P,1e-30) @ f ; dy = Q @ y  (exact: dP/dt = Q P)
__device__ __forceinline__ void site_branch(const v2f* Qm, const v2f* Q2, const v2f* Q3,
                                            const v2f* Q4, float L1Q, float t,
                                            const float* f, float* y, float* dy) {
  float r = L1Q * t * 0.66666667f;  // / 1.5
  int m = 0;
  if (r > 1.f) {
    unsigned u = __float_as_uint(r);
    m = (int)(u >> 23) - 127 + (((u & 0x7fffffu) != 0u) ? 1 : 0);
  }
  const float tau = t * __uint_as_float((unsigned)(127 - m) << 23);
  const float t2s = tau * tau, t3s = t2s * tau, t4s = t2s * t2s;
  const float c1 = t2s * 0.5f, c2 = t3s * (1.f/6.f);
  const float d0 = t4s * (1.f/24.f);
  const float d1 = t4s * tau * (1.f/120.f);
  const float d2 = t4s * t2s * (1.f/720.f);
  const float d3 = t4s * t3s * (1.f/5040.f);
  const float d4 = t4s * t4s * (1.f/40320.f);

  // T = I + tau*Q + c1*Q2 + c2*Q3 ; C1 = d0*I + d1*Q + d2*Q2 + d3*Q3 + d4*Q4
  v2f T[8], C1[8];
#pragma unroll
  for (int ip = 0; ip < 8; ++ip) {
    T[ip]  = v2fma(mkv2(c2,c2), Q3[ip], v2fma(mkv2(c1,c1), Q2[ip], mkv2(tau,tau) * Qm[ip]));
    C1[ip] = v2fma(mkv2(d4,d4), Q4[ip],
             v2fma(mkv2(d3,d3), Q3[ip],
             v2fma(mkv2(d2,d2), Q2[ip], mkv2(d1,d1) * Qm[ip])));
  }
  T[0].x += 1.f;  T[2].y += 1.f;  T[5].x += 1.f;  T[7].y += 1.f;
  C1[0].x += d0;  C1[2].y += d0;  C1[5].x += d0;  C1[7].y += d0;
  mm4v_acc(T, Q4, C1);           // T = Taylor-8 of expm(Q*tau)

  for (int k = 0; k < m; ++k) {  // divergent trip count: exec-masked, ok
    v2f S[8];
    mm4v(S, T, T);
#pragma unroll
    for (int ip = 0; ip < 8; ++ip) T[ip] = S[ip];
  }

  const v2f f01 = mkv2(f[0], f[1]), f23 = mkv2(f[2], f[3]);
  const v2f lo = mkv2(1e-30f, 1e-30f);
#pragma unroll
  for (int i = 0; i < 4; ++i) {
    v2f a = v2max(T[2*i], lo) * f01;
    a = v2fma(v2max(T[2*i+1], lo), f23, a);
    y[i] = a.x + a.y;
  }
#pragma unroll
  for (int i = 0; i < 4; ++i) {
    v2f a = Qm[2*i] * mkv2(y[0], y[1]);
    a = v2fma(Qm[2*i+1], mkv2(y[2], y[3]), a);
    dy[i] = a.x + a.y;
  }
}

// Prep: U0pk[jp*256+s] = half2(u_{2jp,s}, u_{2jp+1,s}), u = b1 + sp@W1[2:18].
// Block = one jp (32 blocks); also packs W1 rows (bid 0) and Wq 12-col (bid 1).
__global__ __launch_bounds__(256) void prep_kernel(
    const float* __restrict__ spg, const float* __restrict__ W1g,
    const float* __restrict__ b1g, const float* __restrict__ Wqg,
    const float* __restrict__ bqg,
    __half2* __restrict__ U0pk, float4* __restrict__ W1pk,
    float* __restrict__ Wqp, float* __restrict__ bqp)
{
  const int jp = blockIdx.x;     // 0..31
  const int s  = threadIdx.x;    // 0..255
  const int j0 = 2*jp, j1 = 2*jp + 1;
  float u0 = b1g[j0], u1 = b1g[j1];
#pragma unroll
  for (int k4 = 0; k4 < 4; ++k4) {
    float4 v4 = reinterpret_cast<const float4*>(spg)[s*4 + k4];
    const float* W0 = W1g + (2 + 4*k4)*64;
    u0 = fmaf(v4.x, W0[j0],       u0);  u1 = fmaf(v4.x, W0[j1],       u1);
    u0 = fmaf(v4.y, W0[64 + j0],  u0);  u1 = fmaf(v4.y, W0[64 + j1],  u1);
    u0 = fmaf(v4.z, W0[128 + j0], u0);  u1 = fmaf(v4.z, W0[128 + j1], u1);
    u0 = fmaf(v4.w, W0[192 + j0], u0);  u1 = fmaf(v4.w, W0[192 + j1], u1);
  }
  U0pk[jp*256 + s] = __float22half2_rn(make_float2(u0, u1));

  if (jp == 0 && s < 32) {
    // W1pk[p] = (w1a_{2p}, w1a_{2p+1}, w1b_{2p}, w1b_{2p+1})
    W1pk[s] = make_float4(W1g[2*s], W1g[2*s+1], W1g[64 + 2*s], W1g[65 + 2*s]);
  }
  if (jp == 1 && s < 64) {
    const int cmap[12] = {1,2,3,4,6,7,8,9,11,12,13,14};
#pragma unroll
    for (int k = 0; k < 12; ++k) Wqp[s*12 + k] = Wqg[s*16 + cmap[k]];
    if (s == 0) {
#pragma unroll
      for (int k = 0; k < 12; ++k) bqp[k] = bqg[cmap[k]];
    }
  }
}

// block = one v (1024 blocks), thread = one site s (256 threads).
// Plain __launch_bounds__(256): (256,4) caused 64-VGPR clamp + spills (R3);
// register hoists caused 196 VGPR (R4). u lives in LDS (f16x2), W1 rows in LDS.
__global__ __launch_bounds__(256) void mlme_kernel(
    const float* __restrict__ c1g, const float* __restrict__ c2g,
    const float* __restrict__ lf1g, const float* __restrict__ lf2g,
    const float* __restrict__ Wpg, const float* __restrict__ bpg,
    const __half2* __restrict__ U0pk, const float4* __restrict__ W1pk,
    const float* __restrict__ Wqp, const float* __restrict__ bqp,
    float* __restrict__ outg)
{
  __shared__ __half2 uLDS[8192];   // 32 KB: [jp*256 + s]
  __shared__ float4 w1LDS[32];     // 512 B
  __shared__ float sred[8];
  __shared__ float sAB[2];
  __shared__ float sPQ[8];

  const int v = blockIdx.x;
  const int tid = threadIdx.x;
  const int lane = tid & 63;
  const int wid = tid >> 6;

  if (tid == 0) {
    float c10 = c1g[2*v], c11 = c1g[2*v+1];
    float c20 = c2g[2*v], c21 = c2g[2*v+1];
    float pn = sqrtf(c10*c10 + c11*c11 + EPSf);
    float qn = sqrtf(c20*c20 + c21*c21 + EPSf);
    float p0 = c10, p1 = c11, q0 = c20, q1 = c21;
    if (pn > qn) { float rr = qn/pn; p0 = c10*rr; p1 = c11*rr; }
    if (qn > pn) { float rr = pn/qn; q0 = c20*rr; q1 = c21*rr; }
    sPQ[0]=p0; sPQ[1]=p1; sPQ[2]=q0; sPQ[3]=q1;
    sPQ[4]=c10; sPQ[5]=c11; sPQ[6]=c20; sPQ[7]=c21;
    sAB[0]=0.5f; sAB[1]=0.5f;
  }

  // stage u table (32 KB) and W1 rows into LDS, strided to keep global coalesced
  {
    const float4* src = reinterpret_cast<const float4*>(U0pk);
    float4* dst = reinterpret_cast<float4*>(uLDS);
#pragma unroll
    for (int k = 0; k < 8; ++k) dst[tid + 256*k] = src[tid + 256*k];
    if (tid < 32) w1LDS[tid] = W1pk[tid];
  }

  // f = exp(log_felsenstein) per thread, once
  float f1[4], f2[4];
  {
    float4 a = reinterpret_cast<const float4*>(lf1g)[v*256 + tid];
    float4 b = reinterpret_cast<const float4*>(lf2g)[v*256 + tid];
    f1[0]=__expf(a.x); f1[1]=__expf(a.y); f1[2]=__expf(a.z); f1[3]=__expf(a.w);
    f2[0]=__expf(b.x); f2[1]=__expf(b.y); f2[2]=__expf(b.z); f2[3]=__expf(b.w);
  }
  __syncthreads();

  const v2f* Wqp2 = reinterpret_cast<const v2f*>(Wqp);   // [j][6]
  const v2f* Wp2  = reinterpret_cast<const v2f*>(Wpg);   // [j][2]
  const v2f* bq2  = reinterpret_cast<const v2f*>(bqp);   // [6]
  const v2f* bp2  = reinterpret_cast<const v2f*>(bpg);   // [2]

  for (int it = 0; it < 3; ++it) {
    const float alpha = sAB[0], beta = sAB[1];
    const float p0=sPQ[0], p1=sPQ[1], q0=sPQ[2], q1=sPQ[3];
    const float c10=sPQ[4], c11=sPQ[5], c20=sPQ[6], c21=sPQ[7];
    const float mid0 = p0*alpha + q0*(1.f-alpha);
    const float mid1 = p1*alpha + q1*(1.f-alpha);
    const float par0 = mid0*beta, par1 = mid1*beta;
    const float d10 = c10-par0, d11 = c11-par1;
    const float d20 = c20-par0, d21 = c21-par1;
    const float t1 = sqrtf(d10*d10 + d11*d11 + EPSf);
    const float t2 = sqrtf(d20*d20 + d21*d21 + EPSf);

    // ---- MLP: h = relu(u + par.W1[:2]); 12 q-cols + 4 p-cols ----
    v2f q2[6], p2[2];
#pragma unroll
    for (int k = 0; k < 6; ++k) q2[k] = bq2[k];
    p2[0] = bp2[0]; p2[1] = bp2[1];
    const v2f pz0 = mkv2(par0, par0), pz1 = mkv2(par1, par1);
#pragma unroll 8
    for (int jp = 0; jp < 32; ++jp) {
      float2 uf = __half22float2(uLDS[jp*256 + tid]);
      float4 w = w1LDS[jp];
      v2f hv = v2fma(pz1, mkv2(w.z, w.w), v2fma(pz0, mkv2(w.x, w.y), mkv2(uf.x, uf.y)));
      hv = v2max(hv, mkv2(0.f, 0.f));
      const v2f h0 = mkv2(hv.x, hv.x), h1 = mkv2(hv.y, hv.y);
      const int j0 = 2*jp, j1 = 2*jp + 1;
#pragma unroll
      for (int k = 0; k < 6; ++k) q2[k] = v2fma(h0, Wqp2[j0*6 + k], q2[k]);
      p2[0] = v2fma(h0, Wp2[j0*2 + 0], p2[0]);
      p2[1] = v2fma(h0, Wp2[j0*2 + 1], p2[1]);
#pragma unroll
      for (int k = 0; k < 6; ++k) q2[k] = v2fma(h1, Wqp2[j1*6 + k], q2[k]);
      p2[0] = v2fma(h1, Wp2[j1*2 + 0], p2[0]);
      p2[1] = v2fma(h1, Wp2[j1*2 + 1], p2[1]);
    }

    // ---- softplus on the 12 off-diagonals; build Q and its 1-norm ----
    float o[12];
#pragma unroll
    for (int k = 0; k < 6; ++k) {
      v2f qq = q2[k];
      float x0 = qq.x, x1 = qq.y;
      o[2*k]   = fmaxf(x0, 0.f) + __logf(1.f + __expf(-fabsf(x0)));
      o[2*k+1] = fmaxf(x1, 0.f) + __logf(1.f + __expf(-fabsf(x1)));
    }
    const float rs0 = o[0]+o[1]+o[2],  rs1 = o[3]+o[4]+o[5];
    const float rs2 = o[6]+o[7]+o[8],  rs3 = o[9]+o[10]+o[11];
    v2f Qm[8];
    Qm[0] = mkv2(-rs0, o[0]);  Qm[1] = mkv2(o[1], o[2]);
    Qm[2] = mkv2(o[3], -rs1);  Qm[3] = mkv2(o[4], o[5]);
    Qm[4] = mkv2(o[6], o[7]);  Qm[5] = mkv2(-rs2, o[8]);
    Qm[6] = mkv2(o[9], o[10]); Qm[7] = mkv2(o[11], -rs3);
    const float cs0 = rs0 + o[3] + o[6] + o[9];
    const float cs1 = o[0] + rs1 + o[7] + o[10];
    const float cs2 = o[1] + o[4] + rs2 + o[11];
    const float cs3 = o[2] + o[5] + o[8] + rs3;
    const float L1Q = fmaxf(fmaxf(cs0, cs1), fmaxf(cs2, cs3));

    // unnormalized stationary probs (normalization cancels in gradient ratio)
    float st[4];
    {
      float pr0 = p2[0].x, pr1 = p2[0].y, pr2 = p2[1].x, pr3 = p2[1].y;
      float mx = fmaxf(fmaxf(pr0, pr1), fmaxf(pr2, pr3));
      st[0]=__expf(pr0-mx); st[1]=__expf(pr1-mx); st[2]=__expf(pr2-mx); st[3]=__expf(pr3-mx);
    }

    // shared powers
    v2f Q2m[8], Q3m[8], Q4m[8];
    mm4v(Q2m, Qm, Qm);
    mm4v(Q3m, Q2m, Qm);
    mm4v(Q4m, Q2m, Q2m);

    float y1[4], dy1[4], y2[4], dy2[4];
    site_branch(Qm, Q2m, Q3m, Q4m, L1Q, t1, f1, y1, dy1);
    site_branch(Qm, Q2m, Q3m, Q4m, L1Q, t2, f2, y2, dy2);

    // g_k = sum_a dy_k[a] * (other y)[a] * st[a] / sum_a y1 y2 st
    float den = 0.f, num1 = 0.f, num2 = 0.f;
#pragma unroll
    for (int a = 0; a < 4; ++a) {
      float ys2 = y2[a] * st[a];
      den  = fmaf(y1[a],  ys2, den);
      num1 = fmaf(dy1[a], ys2, num1);
      num2 = fmaf(y1[a] * st[a], dy2[a], num2);
    }
    const float invden = 1.f / den;
    float g1c = num1 * invden;
    float g2c = num2 * invden;

#pragma unroll
    for (int off = 32; off > 0; off >>= 1) {
      g1c += __shfl_xor(g1c, off, 64);
      g2c += __shfl_xor(g2c, off, 64);
    }
    if (lane == 0) { sred[wid*2+0] = g1c; sred[wid*2+1] = g2c; }
    __syncthreads();
    if (tid == 0) {
      float g1 = sred[0]+sred[2]+sred[4]+sred[6];
      float g2 = sred[1]+sred[3]+sred[5]+sred[7];
      float db1da = ((par0-c10)*(p0-q0) + (par1-c11)*(p1-q1)) * beta / t1;
      float db2da = ((par0-c20)*(p0-q0) + (par1-c21)*(p1-q1)) * beta / t2;
      float db1db = ((par0-c10)*mid0 + (par1-c11)*mid1) / t1;
      float db2db = ((par0-c20)*mid0 + (par1-c21)*mid1) / t2;
      float ga = g1*db1da + g2*db2da;
      float gb = g1*db1db + g2*db2db;
      ga = fminf(1.f, fmaxf(-1.f, ga));
      gb = fminf(1.f, fmaxf(-1.f, gb));
      sAB[0] = fminf(1.f, fmaxf(0.f, alpha + 0.1f*ga));
      sAB[1] = fminf(1.f, fmaxf(0.f, beta  + 0.1f*gb));
    }
    __syncthreads();
  }

  if (tid == 0) {
    const float alpha = sAB[0], beta = sAB[1];
    const float p0=sPQ[0], p1=sPQ[1], q0=sPQ[2], q1=sPQ[3];
    float mid0 = p0*alpha + q0*(1.f-alpha);
    float mid1 = p1*alpha + q1*(1.f-alpha);
    outg[2*v]   = mid0*beta;
    outg[2*v+1] = mid1*beta;
  }
}

extern "C" void kernel_launch(void* const* d_in, const int* in_sizes, int n_in,
                              void* d_out, int out_size, void* d_ws, size_t ws_size,
                              hipStream_t stream) {
  (void)in_sizes; (void)n_in; (void)ws_size; (void)out_size;
  const float* c1  = (const float*)d_in[0];
  const float* c2  = (const float*)d_in[1];
  const float* lf1 = (const float*)d_in[2];
  const float* lf2 = (const float*)d_in[3];
  const float* sp  = (const float*)d_in[4];
  const float* W1  = (const float*)d_in[5];
  const float* b1  = (const float*)d_in[6];
  const float* Wq  = (const float*)d_in[7];
  const float* bq  = (const float*)d_in[8];
  const float* Wp  = (const float*)d_in[9];
  const float* bp  = (const float*)d_in[10];
  float* out = (float*)d_out;

  __half2* U0pk = (__half2*)d_ws;                          // 8192*4 = 32 KB
  float4*  W1pk = (float4*)((char*)d_ws + 32768);          // 32*16 = 512 B
  float*   Wqp  = (float*)((char*)d_ws + 33280);           // 64*12*4 = 3072 B
  float*   bqp  = (float*)((char*)d_ws + 36352);           // 48 B

  prep_kernel<<<dim3(32), dim3(256), 0, stream>>>(sp, W1, b1, Wq, bq,
                                                  U0pk, W1pk, Wqp, bqp);
  mlme_kernel<<<dim3(1024), dim3(256), 0, stream>>>(
      c1, c2, lf1, lf2, Wp, bp, U0pk, W1pk, Wqp, bqp, out);
}